// Round 1
// baseline (184.451 us; speedup 1.0000x reference)
//
#include <hip/hip_runtime.h>
#include <stdint.h>

#define TB 256

typedef __bf16 bf16x8 __attribute__((ext_vector_type(8)));
typedef float f32x4 __attribute__((ext_vector_type(4)));

__device__ __forceinline__ unsigned short f2bf(float f) {
  uint32_t u = __builtin_bit_cast(uint32_t, f);
  u += 0x7fffu + ((u >> 16) & 1u);
  return (unsigned short)(u >> 16);
}

// ---------------- kernel: x f32 -> bf16 ----------------
__global__ __launch_bounds__(TB) void k_xcvt(const float* __restrict__ x,
                                             unsigned short* __restrict__ xbf) {
  int idx = blockIdx.x * TB + threadIdx.x;  // 1,048,576 threads, 8 elems each
  const float4* xin = reinterpret_cast<const float4*>(x);
  float4 a = xin[idx * 2], b = xin[idx * 2 + 1];
  uint32_t p0 = f2bf(a.x) | ((uint32_t)f2bf(a.y) << 16);
  uint32_t p1 = f2bf(a.z) | ((uint32_t)f2bf(a.w) << 16);
  uint32_t p2 = f2bf(b.x) | ((uint32_t)f2bf(b.y) << 16);
  uint32_t p3 = f2bf(b.z) | ((uint32_t)f2bf(b.w) << 16);
  reinterpret_cast<uint4*>(xbf)[idx] = make_uint4(p0, p1, p2, p3);
}

// ---------------- kernel: weight transpose+convert ----------------
// W_lvl2 [25][2048][41] f32 -> wlt bf16 [25][48][2048] (pad cols 41..47 = 0)
// W_root [2048][26]     f32 -> wrt bf16 [32][2048]     (pad cols 26..31 = 0)
__global__ __launch_bounds__(TB) void k_wt(const float* __restrict__ wl,
                                           const float* __restrict__ wr,
                                           unsigned short* __restrict__ wlt,
                                           unsigned short* __restrict__ wrt) {
  __shared__ float ld_f[2624];
  int bid = blockIdx.x;
  int t = threadIdx.x;
  if (bid < 800) {
    int n = bid / 32, dt = bid % 32, d0 = dt * 64;
    const float* src = wl + ((size_t)n * 2048 + d0) * 41;
    for (int i = 0; i < 11; i++) { int lin = t + TB * i; if (lin < 2624) ld_f[lin] = src[lin]; }
    __syncthreads();
    unsigned short* dst = wlt + (size_t)n * 48 * 2048 + d0;
    for (int i = 0; i < 12; i++) {
      int lin = t + TB * i;  // 3072 = 48*64
      int wc = lin >> 6, d = lin & 63;
      float v = (wc < 41) ? ld_f[d * 41 + wc] : 0.f;
      dst[(size_t)wc * 2048 + d] = f2bf(v);
    }
  } else {
    int dt = bid - 800, d0 = dt * 64;
    const float* src = wr + (size_t)d0 * 26;
    for (int i = 0; i < 7; i++) { int lin = t + TB * i; if (lin < 1664) ld_f[lin] = src[lin]; }
    __syncthreads();
    unsigned short* dst = wrt + d0;
    for (int i = 0; i < 8; i++) {
      int lin = t + TB * i;  // 2048 = 32*64
      int wc = lin >> 6, d = lin & 63;
      float v = (wc < 26) ? ld_f[d * 26 + wc] : 0.f;
      dst[(size_t)wc * 2048 + d] = f2bf(v);
    }
  }
}

// ---------------- kernel: normalize labels (int32 or int64 upload) ----------------
__global__ __launch_bounds__(TB) void k_labfix(const int* __restrict__ lin_,
                                               int* __restrict__ lout) {
  __shared__ int orred;
  int t = threadIdx.x;
  if (t == 0) orred = 0;
  __syncthreads();
  int acc = 0;
  for (int i = t; i < 2048; i += TB) acc |= lin_[2 * i + 1];  // stays within 4096 ints
  atomicOr(&orred, acc);
  __syncthreads();
  bool i64 = (orred == 0);
  for (int i = t; i < 4096; i += TB) lout[i] = i64 ? lin_[2 * i] : lin_[i];
}

// ---------------- kernel: root GEMM, split-K, atomic accumulate ----------------
__global__ __launch_bounds__(TB) void k_rootg(const unsigned short* __restrict__ xbf,
                                              const unsigned short* __restrict__ wrt,
                                              float* __restrict__ wslog) {
  __shared__ __align__(16) unsigned char lds[16384 + 4096];
  int bid = blockIdx.x;  // 256 = 32 row-tiles * 8 k-slices
  int rt = bid >> 3, ks8 = bid & 7;
  int r0 = rt * 128, kbase = ks8 * 256;
  int tid = threadIdx.x, lane = tid & 63, wave = tid >> 6;
  int lq = lane >> 4, lr = lane & 15;
  f32x4 acc[2][2] = {};
  const unsigned short* xg = xbf + (size_t)r0 * 2048;
  for (int kk = kbase; kk < kbase + 256; kk += 64) {
#pragma unroll
    for (int i = 0; i < 4; i++) {
      int lin = tid + TB * i;
      int row = lin >> 3, kb = lin & 7;
      uint4 v = *reinterpret_cast<const uint4*>(xg + (size_t)row * 2048 + kk + kb * 8);
      *reinterpret_cast<uint4*>(lds + row * 128 + ((kb ^ (row & 7)) << 4)) = v;
    }
    {
      int wc = tid >> 3, kb = tid & 7;
      uint4 v = *reinterpret_cast<const uint4*>(wrt + (size_t)wc * 2048 + kk + kb * 8);
      *reinterpret_cast<uint4*>(lds + 16384 + wc * 128 + ((kb ^ (wc & 7)) << 4)) = v;
    }
    __syncthreads();
#pragma unroll
    for (int ks = 0; ks < 2; ks++) {
      bf16x8 af[2], bx[2];
#pragma unroll
      for (int mt = 0; mt < 2; mt++) {
        int wc = mt * 16 + lr;
        af[mt] = *reinterpret_cast<const bf16x8*>(lds + 16384 + wc * 128 + ((((ks << 2) | lq) ^ (wc & 7)) << 4));
      }
#pragma unroll
      for (int nt = 0; nt < 2; nt++) {
        int row = wave * 32 + nt * 16 + lr;
        bx[nt] = *reinterpret_cast<const bf16x8*>(lds + row * 128 + ((((ks << 2) | lq) ^ (row & 7)) << 4));
      }
#pragma unroll
      for (int mt = 0; mt < 2; mt++)
#pragma unroll
        for (int nt = 0; nt < 2; nt++)
          acc[mt][nt] = __builtin_amdgcn_mfma_f32_16x16x32_bf16(af[mt], bx[nt], acc[mt][nt], 0, 0, 0);
    }
    __syncthreads();
  }
#pragma unroll
  for (int nt = 0; nt < 2; nt++) {
    int b = r0 + wave * 32 + nt * 16 + lr;
#pragma unroll
    for (int mt = 0; mt < 2; mt++)
#pragma unroll
      for (int r = 0; r < 4; r++) {
        int wc = mt * 16 + lq * 4 + r;
        if (wc < 26) atomicAdd(&wslog[(size_t)b * 32 + wc], acc[mt][nt][r]);
      }
  }
}

// ---------------- kernel: root softmax + prob store + ce_root ----------------
__global__ __launch_bounds__(TB) void k_rootsm(const float* __restrict__ wslog,
                                               const float* __restrict__ br,
                                               const int* __restrict__ labels,
                                               float* __restrict__ rootp,
                                               float* __restrict__ pengl) {
  int b = blockIdx.x * TB + threadIdx.x;  // 4096 threads
  float lgs[26];
  float m = -1e30f;
#pragma unroll
  for (int c = 0; c < 26; c++) { lgs[c] = wslog[(size_t)b * 32 + c] + br[c]; m = fmaxf(m, lgs[c]); }
  float s = 0.f;
#pragma unroll
  for (int c = 0; c < 26; c++) s += expf(lgs[c] - m);
  float ls = logf(s);
#pragma unroll
  for (int c = 0; c < 26; c++) rootp[(size_t)b * 32 + c] = expf(lgs[c] - m - ls);
  int lab = labels[b];
  int j = lab / 40;
  float pen = 0.f;
#pragma unroll
  for (int c = 0; c < 26; c++) if (c == j + 1) pen = -(lgs[c] - m - ls);
  for (int off = 32; off; off >>= 1) pen += __shfl_down(pen, off);
  __shared__ float red[4];
  int lane = threadIdx.x & 63, wave = threadIdx.x >> 6;
  if (lane == 0) red[wave] = pen;
  __syncthreads();
  if (threadIdx.x == 0) atomicAdd(pengl, (red[0] + red[1] + red[2] + red[3]) * (1.f / 4096.f));
}

// ---------------- kernel: lvl2 grouped GEMM + softmax + out + penalty ----------------
__global__ __launch_bounds__(TB) void k_lvl2(const unsigned short* __restrict__ xbf,
                                             const unsigned short* __restrict__ wlt,
                                             const float* __restrict__ bl,
                                             const int* __restrict__ labels,
                                             const float* __restrict__ rootp,
                                             float* __restrict__ out,
                                             float* __restrict__ pengl) {
  __shared__ __align__(16) unsigned char lds[16384 + 6144];
  int bid = blockIdx.x;                       // 800 = 32 row-tiles * 25 groups
  int swz = (bid & 7) * 100 + (bid >> 3);     // XCD-chunked, bijective (800 = 8*100)
  int rt = swz / 25, n = swz % 25;
  int r0 = rt * 128;
  int tid = threadIdx.x, lane = tid & 63, wave = tid >> 6;
  int lq = lane >> 4, lr = lane & 15;
  f32x4 acc[3][2] = {};
  const unsigned short* xg = xbf + (size_t)r0 * 2048;
  const unsigned short* wg = wlt + (size_t)n * 48 * 2048;
  for (int kk = 0; kk < 2048; kk += 64) {
#pragma unroll
    for (int i = 0; i < 4; i++) {
      int lin = tid + TB * i;
      int row = lin >> 3, kb = lin & 7;
      uint4 v = *reinterpret_cast<const uint4*>(xg + (size_t)row * 2048 + kk + kb * 8);
      *reinterpret_cast<uint4*>(lds + row * 128 + ((kb ^ (row & 7)) << 4)) = v;
    }
#pragma unroll
    for (int i = 0; i < 2; i++) {
      int lin = tid + TB * i;
      if (lin < 384) {
        int wc = lin >> 3, kb = lin & 7;
        uint4 v = *reinterpret_cast<const uint4*>(wg + (size_t)wc * 2048 + kk + kb * 8);
        *reinterpret_cast<uint4*>(lds + 16384 + wc * 128 + ((kb ^ (wc & 7)) << 4)) = v;
      }
    }
    __syncthreads();
#pragma unroll
    for (int ks = 0; ks < 2; ks++) {
      bf16x8 af[3], bx[2];
#pragma unroll
      for (int mt = 0; mt < 3; mt++) {
        int wc = mt * 16 + lr;
        af[mt] = *reinterpret_cast<const bf16x8*>(lds + 16384 + wc * 128 + ((((ks << 2) | lq) ^ (wc & 7)) << 4));
      }
#pragma unroll
      for (int nt = 0; nt < 2; nt++) {
        int row = wave * 32 + nt * 16 + lr;
        bx[nt] = *reinterpret_cast<const bf16x8*>(lds + row * 128 + ((((ks << 2) | lq) ^ (row & 7)) << 4));
      }
#pragma unroll
      for (int mt = 0; mt < 3; mt++)
#pragma unroll
        for (int nt = 0; nt < 2; nt++)
          acc[mt][nt] = __builtin_amdgcn_mfma_f32_16x16x32_bf16(af[mt], bx[nt], acc[mt][nt], 0, 0, 0);
    }
    __syncthreads();
  }

  // epilogue: bias, row softmax (row lives in 4 lanes: q groups), out, penalty
  float bb[3][4];
#pragma unroll
  for (int mt = 0; mt < 3; mt++)
#pragma unroll
    for (int r = 0; r < 4; r++) {
      int wc = mt * 16 + lq * 4 + r;
      bb[mt][r] = (wc < 41) ? bl[n * 41 + wc] : -1e30f;
    }
  float pen = 0.f;
#pragma unroll
  for (int nt = 0; nt < 2; nt++) {
    int b = r0 + wave * 32 + nt * 16 + lr;
    float lg[3][4];
    float m = -1e30f;
#pragma unroll
    for (int mt = 0; mt < 3; mt++)
#pragma unroll
      for (int r = 0; r < 4; r++) {
        float v = acc[mt][nt][r] + bb[mt][r];
        lg[mt][r] = v;
        m = fmaxf(m, v);
      }
    m = fmaxf(m, __shfl_xor(m, 16));
    m = fmaxf(m, __shfl_xor(m, 32));
    float s = 0.f;
#pragma unroll
    for (int mt = 0; mt < 3; mt++)
#pragma unroll
      for (int r = 0; r < 4; r++) s += expf(lg[mt][r] - m);
    s += __shfl_xor(s, 16);
    s += __shfl_xor(s, 32);
    float ls = logf(s);
    float rp = rootp[(size_t)b * 32 + (n + 1)];
    int lab = labels[b];
    int j = lab / 40;
    int sub = (j == n) ? (lab - j * 40 + 1) : 0;
#pragma unroll
    for (int mt = 0; mt < 3; mt++)
#pragma unroll
      for (int r = 0; r < 4; r++) {
        int wc = mt * 16 + lq * 4 + r;
        float lp = lg[mt][r] - m - ls;
        if (wc >= 1 && wc < 41) out[(size_t)b * 1000 + n * 40 + wc - 1] = expf(lp) * rp;
        if (wc == sub) pen -= lp;
      }
  }
  for (int off = 32; off; off >>= 1) pen += __shfl_down(pen, off);
  float* red = (float*)lds;  // safe: all LDS tile reads completed before last barrier
  if (lane == 0) red[wave] = pen;
  __syncthreads();
  if (tid == 0) atomicAdd(pengl, (red[0] + red[1] + red[2] + red[3]) * (1.f / 8192.f));
}

extern "C" void kernel_launch(void* const* d_in, const int* in_sizes, int n_in,
                              void* d_out, int out_size, void* d_ws, size_t ws_size,
                              hipStream_t stream) {
  const float* x = (const float*)d_in[0];
  const int* labels_raw = (const int*)d_in[1];
  const float* wroot = (const float*)d_in[2];
  const float* broot = (const float*)d_in[3];
  const float* wlvl2 = (const float*)d_in[4];
  const float* blvl2 = (const float*)d_in[5];
  float* out = (float*)d_out;
  float* pengl = out + 4096000;

  char* ws = (char*)d_ws;
  unsigned short* xbf = (unsigned short*)ws;                              // 16,777,216 B
  unsigned short* wlt = (unsigned short*)(ws + 16777216);                 //  4,915,200 B
  unsigned short* wrt = (unsigned short*)(ws + 16777216 + 4915200);       //    131,072 B
  float* wslog = (float*)(ws + 16777216 + 4915200 + 131072);              //    524,288 B
  float* rootp = (float*)(ws + 16777216 + 4915200 + 131072 + 524288);     //    524,288 B
  int* lab32 = (int*)(ws + 16777216 + 4915200 + 131072 + 524288 + 524288);//     16,384 B

  hipMemsetAsync(wslog, 0, 4096 * 32 * 4, stream);
  hipMemsetAsync(pengl, 0, 4, stream);
  k_labfix<<<1, TB, 0, stream>>>(labels_raw, lab32);
  k_xcvt<<<4096, TB, 0, stream>>>(x, xbf);
  k_wt<<<832, TB, 0, stream>>>(wlvl2, wroot, wlt, wrt);
  k_rootg<<<256, TB, 0, stream>>>(xbf, wrt, wslog);
  k_rootsm<<<16, TB, 0, stream>>>(wslog, broot, lab32, rootp, pengl);
  k_lvl2<<<800, TB, 0, stream>>>(xbf, wlt, blvl2, lab32, rootp, out, pengl);
}

// Round 3
// 173.087 us; speedup vs baseline: 1.0657x; 1.0657x over previous
//
#include <hip/hip_runtime.h>
#include <stdint.h>

#define TB 256

typedef __bf16 bf16x8 __attribute__((ext_vector_type(8)));
typedef float f32x4 __attribute__((ext_vector_type(4)));

#define AS1 __attribute__((address_space(1)))
#define AS3 __attribute__((address_space(3)))
// direct global->LDS, 16B per lane; LDS dest = wave-uniform base + lane*16
#define GLOAD16(gp, lp) __builtin_amdgcn_global_load_lds( \
    (const AS1 unsigned int*)(gp), (AS3 unsigned int*)(lp), 16, 0, 0)

__device__ __forceinline__ unsigned short f2bf(float f) {
  uint32_t u = __builtin_bit_cast(uint32_t, f);
  u += 0x7fffu + ((u >> 16) & 1u);
  return (unsigned short)(u >> 16);
}

// ---------------- kernel: x f32 -> bf16 ----------------
__global__ __launch_bounds__(TB) void k_xcvt(const float* __restrict__ x,
                                             unsigned short* __restrict__ xbf) {
  int idx = blockIdx.x * TB + threadIdx.x;  // 1,048,576 threads, 8 elems each
  const float4* xin = reinterpret_cast<const float4*>(x);
  float4 a = xin[idx * 2], b = xin[idx * 2 + 1];
  uint32_t p0 = f2bf(a.x) | ((uint32_t)f2bf(a.y) << 16);
  uint32_t p1 = f2bf(a.z) | ((uint32_t)f2bf(a.w) << 16);
  uint32_t p2 = f2bf(b.x) | ((uint32_t)f2bf(b.y) << 16);
  uint32_t p3 = f2bf(b.z) | ((uint32_t)f2bf(b.w) << 16);
  reinterpret_cast<uint4*>(xbf)[idx] = make_uint4(p0, p1, p2, p3);
}

// ---------------- kernel: weight transpose+convert ----------------
// W_lvl2 [25][2048][41] f32 -> wlt bf16 [25][48][2048] (pad cols 41..47 = 0)
// W_root [2048][26]     f32 -> wrt bf16 [32][2048]     (pad cols 26..31 = 0)
__global__ __launch_bounds__(TB) void k_wt(const float* __restrict__ wl,
                                           const float* __restrict__ wr,
                                           unsigned short* __restrict__ wlt,
                                           unsigned short* __restrict__ wrt) {
  __shared__ float ld_f[2624];
  int bid = blockIdx.x;
  int t = threadIdx.x;
  if (bid < 800) {
    int n = bid / 32, dt = bid % 32, d0 = dt * 64;
    const float* src = wl + ((size_t)n * 2048 + d0) * 41;
    for (int i = 0; i < 11; i++) { int lin = t + TB * i; if (lin < 2624) ld_f[lin] = src[lin]; }
    __syncthreads();
    unsigned short* dst = wlt + (size_t)n * 48 * 2048 + d0;
    for (int i = 0; i < 12; i++) {
      int lin = t + TB * i;  // 3072 = 48*64
      int wc = lin >> 6, d = lin & 63;
      float v = (wc < 41) ? ld_f[d * 41 + wc] : 0.f;
      dst[(size_t)wc * 2048 + d] = f2bf(v);
    }
  } else {
    int dt = bid - 800, d0 = dt * 64;
    const float* src = wr + (size_t)d0 * 26;
    for (int i = 0; i < 7; i++) { int lin = t + TB * i; if (lin < 1664) ld_f[lin] = src[lin]; }
    __syncthreads();
    unsigned short* dst = wrt + d0;
    for (int i = 0; i < 8; i++) {
      int lin = t + TB * i;  // 2048 = 32*64
      int wc = lin >> 6, d = lin & 63;
      float v = (wc < 26) ? ld_f[d * 26 + wc] : 0.f;
      dst[(size_t)wc * 2048 + d] = f2bf(v);
    }
  }
}

// ---------------- kernel: normalize labels + zero penalty ----------------
__global__ __launch_bounds__(TB) void k_labfix(const int* __restrict__ lin_,
                                               int* __restrict__ lout,
                                               float* __restrict__ pengl) {
  __shared__ int orred;
  int t = threadIdx.x;
  if (t == 0) { orred = 0; pengl[0] = 0.f; }
  __syncthreads();
  int acc = 0;
  for (int i = t; i < 2048; i += TB) acc |= lin_[2 * i + 1];  // stays within 4096 ints
  atomicOr(&orred, acc);
  __syncthreads();
  bool i64 = (orred == 0);
  for (int i = t; i < 4096; i += TB) lout[i] = i64 ? lin_[2 * i] : lin_[i];
}

// stage one 128x64 x-tile (linear LDS dest, source pre-swizzled so that
// LDS[row][s] holds global chunk s^(row&7); read side XORs the same way)
__device__ __forceinline__ void stage_x(const unsigned short* xg, unsigned char* lbuf,
                                        int kk, int tid, int wavebase) {
#pragma unroll
  for (int i = 0; i < 4; i++) {
    int c = i * 256 + tid;
    int row = c >> 3, s = c & 7;
    const unsigned short* gp = xg + (size_t)row * 2048 + kk + ((s ^ (row & 7)) << 3);
    GLOAD16(gp, lbuf + (size_t)(i * 256 + wavebase) * 16);
  }
}

// ---------------- kernel: root GEMM, split-K, 2-phase pipelined ----------------
__global__ __launch_bounds__(TB) void k_rootg(const unsigned short* __restrict__ xbf,
                                              const unsigned short* __restrict__ wrt,
                                              float* __restrict__ wslog) {
  __shared__ __align__(16) unsigned char lds[2][20480];  // 16K x + 4K w per buf
  int bid = blockIdx.x;  // 256 = 32 row-tiles * 8 k-slices
  int rt = bid >> 3, ks8 = bid & 7;
  int r0 = rt * 128, kbase = ks8 * 256;
  int tid = threadIdx.x, lane = tid & 63, wave = tid >> 6;
  int wavebase = wave * 64;
  int lq = lane >> 4, lr = lane & 15;
  f32x4 acc[2][2] = {};
  const unsigned short* xg = xbf + (size_t)r0 * 2048;

#define STAGE_R(bufi, kk)                                                        \
  do {                                                                           \
    stage_x(xg, lds[bufi], (kk), tid, wavebase);                                 \
    int wc = tid >> 3, s = tid & 7;                                              \
    const unsigned short* gp = wrt + (size_t)wc * 2048 + (kk) + ((s ^ (wc & 7)) << 3); \
    GLOAD16(gp, lds[bufi] + 16384 + (size_t)wavebase * 16);                      \
  } while (0)

  STAGE_R(0, kbase);
  __syncthreads();
  int cur = 0;
#pragma unroll
  for (int t = 0; t < 4; t++) {
    if (t < 3) STAGE_R(cur ^ 1, kbase + (t + 1) * 64);
    unsigned char* base = &lds[cur][0];
#pragma unroll
    for (int ks = 0; ks < 2; ks++) {
      bf16x8 af[2], bx[2];
#pragma unroll
      for (int mt = 0; mt < 2; mt++) {
        int wc = mt * 16 + lr;
        af[mt] = *reinterpret_cast<const bf16x8*>(base + 16384 + wc * 128 + ((((ks << 2) | lq) ^ (wc & 7)) << 4));
      }
#pragma unroll
      for (int nt = 0; nt < 2; nt++) {
        int row = wave * 32 + nt * 16 + lr;
        bx[nt] = *reinterpret_cast<const bf16x8*>(base + row * 128 + ((((ks << 2) | lq) ^ (row & 7)) << 4));
      }
#pragma unroll
      for (int mt = 0; mt < 2; mt++)
#pragma unroll
        for (int nt = 0; nt < 2; nt++)
          acc[mt][nt] = __builtin_amdgcn_mfma_f32_16x16x32_bf16(af[mt], bx[nt], acc[mt][nt], 0, 0, 0);
    }
    __syncthreads();
    cur ^= 1;
  }
#pragma unroll
  for (int nt = 0; nt < 2; nt++) {
    int b = r0 + wave * 32 + nt * 16 + lr;
#pragma unroll
    for (int mt = 0; mt < 2; mt++)
#pragma unroll
      for (int r = 0; r < 4; r++) {
        int wc = mt * 16 + lq * 4 + r;
        if (wc < 26) atomicAdd(&wslog[(size_t)b * 32 + wc], acc[mt][nt][r]);
      }
  }
}

// ---------------- kernel: root softmax + prob store + ce_root ----------------
__global__ __launch_bounds__(TB) void k_rootsm(const float* __restrict__ wslog,
                                               const float* __restrict__ br,
                                               const int* __restrict__ labels,
                                               float* __restrict__ rootp,
                                               float* __restrict__ pengl) {
  int b = blockIdx.x * TB + threadIdx.x;  // 4096 threads
  float lgs[26];
  float m = -1e30f;
#pragma unroll
  for (int c = 0; c < 26; c++) { lgs[c] = wslog[(size_t)b * 32 + c] + br[c]; m = fmaxf(m, lgs[c]); }
  float s = 0.f;
#pragma unroll
  for (int c = 0; c < 26; c++) s += expf(lgs[c] - m);
  float ls = logf(s);
#pragma unroll
  for (int c = 0; c < 26; c++) rootp[(size_t)b * 32 + c] = expf(lgs[c] - m - ls);
  int lab = labels[b];
  int j = lab / 40;
  float pen = 0.f;
#pragma unroll
  for (int c = 0; c < 26; c++) if (c == j + 1) pen = -(lgs[c] - m - ls);
  for (int off = 32; off; off >>= 1) pen += __shfl_down(pen, off);
  __shared__ float red[4];
  int lane = threadIdx.x & 63, wave = threadIdx.x >> 6;
  if (lane == 0) red[wave] = pen;
  __syncthreads();
  if (threadIdx.x == 0) atomicAdd(pengl, (red[0] + red[1] + red[2] + red[3]) * (1.f / 4096.f));
}

// ---------------- kernel: lvl2 grouped GEMM, 2-phase pipelined, fused epilogue ----------------
__global__ __launch_bounds__(TB) void k_lvl2(const unsigned short* __restrict__ xbf,
                                             const unsigned short* __restrict__ wlt,
                                             const float* __restrict__ bl,
                                             const int* __restrict__ labels,
                                             const float* __restrict__ rootp,
                                             float* __restrict__ out,
                                             float* __restrict__ pengl) {
  __shared__ __align__(16) unsigned char lds[2][22528];  // 16K x + 6K w per buf
  int bid = blockIdx.x;                       // 800 = 32 row-tiles * 25 groups
  int swz = (bid & 7) * 100 + (bid >> 3);     // XCD-chunked, bijective (800 = 8*100)
  int rt = swz / 25, n = swz % 25;
  int r0 = rt * 128;
  int tid = threadIdx.x, lane = tid & 63, wave = tid >> 6;
  int wavebase = wave * 64;
  int lq = lane >> 4, lr = lane & 15;
  f32x4 acc[3][2] = {};
  const unsigned short* xg = xbf + (size_t)r0 * 2048;
  const unsigned short* wg = wlt + (size_t)n * 48 * 2048;

#define STAGE_L(bufi, kk)                                                        \
  do {                                                                           \
    stage_x(xg, lds[bufi], (kk), tid, wavebase);                                 \
    {                                                                            \
      int wc = tid >> 3, s = tid & 7;                                            \
      const unsigned short* gp = wg + (size_t)wc * 2048 + (kk) + ((s ^ (wc & 7)) << 3); \
      GLOAD16(gp, lds[bufi] + 16384 + (size_t)wavebase * 16);                    \
    }                                                                            \
    if (tid < 128) {                                                             \
      int c = 256 + tid;                                                         \
      int wc = c >> 3, s = c & 7;                                                \
      const unsigned short* gp = wg + (size_t)wc * 2048 + (kk) + ((s ^ (wc & 7)) << 3); \
      GLOAD16(gp, lds[bufi] + 16384 + (size_t)(256 + wavebase) * 16);            \
    }                                                                            \
  } while (0)

  STAGE_L(0, 0);
  __syncthreads();
  int cur = 0;
  for (int kk = 0; kk < 2048; kk += 64) {
    if (kk + 64 < 2048) STAGE_L(cur ^ 1, kk + 64);
    unsigned char* base = &lds[cur][0];
#pragma unroll
    for (int ks = 0; ks < 2; ks++) {
      bf16x8 af[3], bx[2];
#pragma unroll
      for (int mt = 0; mt < 3; mt++) {
        int wc = mt * 16 + lr;
        af[mt] = *reinterpret_cast<const bf16x8*>(base + 16384 + wc * 128 + ((((ks << 2) | lq) ^ (wc & 7)) << 4));
      }
#pragma unroll
      for (int nt = 0; nt < 2; nt++) {
        int row = wave * 32 + nt * 16 + lr;
        bx[nt] = *reinterpret_cast<const bf16x8*>(base + row * 128 + ((((ks << 2) | lq) ^ (row & 7)) << 4));
      }
#pragma unroll
      for (int mt = 0; mt < 3; mt++)
#pragma unroll
        for (int nt = 0; nt < 2; nt++)
          acc[mt][nt] = __builtin_amdgcn_mfma_f32_16x16x32_bf16(af[mt], bx[nt], acc[mt][nt], 0, 0, 0);
    }
    __syncthreads();
    cur ^= 1;
  }

  // epilogue: bias, row softmax (row lives in 4 lanes: q groups), out, penalty
  float bb[3][4];
#pragma unroll
  for (int mt = 0; mt < 3; mt++)
#pragma unroll
    for (int r = 0; r < 4; r++) {
      int wc = mt * 16 + lq * 4 + r;
      bb[mt][r] = (wc < 41) ? bl[n * 41 + wc] : -1e30f;
    }
  float pen = 0.f;
#pragma unroll
  for (int nt = 0; nt < 2; nt++) {
    int b = r0 + wave * 32 + nt * 16 + lr;
    float lg[3][4];
    float m = -1e30f;
#pragma unroll
    for (int mt = 0; mt < 3; mt++)
#pragma unroll
      for (int r = 0; r < 4; r++) {
        float v = acc[mt][nt][r] + bb[mt][r];
        lg[mt][r] = v;
        m = fmaxf(m, v);
      }
    m = fmaxf(m, __shfl_xor(m, 16));
    m = fmaxf(m, __shfl_xor(m, 32));
    float s = 0.f;
#pragma unroll
    for (int mt = 0; mt < 3; mt++)
#pragma unroll
      for (int r = 0; r < 4; r++) s += expf(lg[mt][r] - m);
    s += __shfl_xor(s, 16);
    s += __shfl_xor(s, 32);
    float ls = logf(s);
    float rp = rootp[(size_t)b * 32 + (n + 1)];
    int lab = labels[b];
    int j = lab / 40;
    int sub = (j == n) ? (lab - j * 40 + 1) : 0;
#pragma unroll
    for (int mt = 0; mt < 3; mt++)
#pragma unroll
      for (int r = 0; r < 4; r++) {
        int wc = mt * 16 + lq * 4 + r;
        float lp = lg[mt][r] - m - ls;
        if (wc >= 1 && wc < 41) out[(size_t)b * 1000 + n * 40 + wc - 1] = expf(lp) * rp;
        if (wc == sub) pen -= lp;
      }
  }
  for (int off = 32; off; off >>= 1) pen += __shfl_down(pen, off);
  float* red = (float*)&lds[0][0];  // safe: all LDS tile reads completed before last barrier
  if (lane == 0) red[wave] = pen;
  __syncthreads();
  if (tid == 0) atomicAdd(pengl, (red[0] + red[1] + red[2] + red[3]) * (1.f / 8192.f));
}

extern "C" void kernel_launch(void* const* d_in, const int* in_sizes, int n_in,
                              void* d_out, int out_size, void* d_ws, size_t ws_size,
                              hipStream_t stream) {
  const float* x = (const float*)d_in[0];
  const int* labels_raw = (const int*)d_in[1];
  const float* wroot = (const float*)d_in[2];
  const float* broot = (const float*)d_in[3];
  const float* wlvl2 = (const float*)d_in[4];
  const float* blvl2 = (const float*)d_in[5];
  float* out = (float*)d_out;
  float* pengl = out + 4096000;

  char* ws = (char*)d_ws;
  unsigned short* xbf = (unsigned short*)ws;                              // 16,777,216 B
  unsigned short* wlt = (unsigned short*)(ws + 16777216);                 //  4,915,200 B
  unsigned short* wrt = (unsigned short*)(ws + 16777216 + 4915200);       //    131,072 B
  float* wslog = (float*)(ws + 16777216 + 4915200 + 131072);              //    524,288 B
  float* rootp = (float*)(ws + 16777216 + 4915200 + 131072 + 524288);     //    524,288 B
  int* lab32 = (int*)(ws + 16777216 + 4915200 + 131072 + 524288 + 524288);//     16,384 B

  hipMemsetAsync(wslog, 0, 4096 * 32 * 4, stream);
  k_labfix<<<1, TB, 0, stream>>>(labels_raw, lab32, pengl);
  k_xcvt<<<4096, TB, 0, stream>>>(x, xbf);
  k_wt<<<832, TB, 0, stream>>>(wlvl2, wroot, wlt, wrt);
  k_rootg<<<256, TB, 0, stream>>>(xbf, wrt, wslog);
  k_rootsm<<<16, TB, 0, stream>>>(wslog, broot, lab32, rootp, pengl);
  k_lvl2<<<800, TB, 0, stream>>>(xbf, wlt, blvl2, lab32, rootp, out, pengl);
}

// Round 4
// 152.765 us; speedup vs baseline: 1.2074x; 1.1330x over previous
//
#include <hip/hip_runtime.h>
#include <stdint.h>

#define TB 256

typedef __bf16 bf16x8 __attribute__((ext_vector_type(8)));
typedef float f32x4 __attribute__((ext_vector_type(4)));

#define AS1 __attribute__((address_space(1)))
#define AS3 __attribute__((address_space(3)))
// direct global->LDS, 16B per lane; LDS dest = wave-uniform base + lane*16
#define GLOAD16(gp, lp) __builtin_amdgcn_global_load_lds( \
    (const AS1 unsigned int*)(gp), (AS3 unsigned int*)(lp), 16, 0, 0)

__device__ __forceinline__ unsigned short f2bf(float f) {
  uint32_t u = __builtin_bit_cast(uint32_t, f);
  u += 0x7fffu + ((u >> 16) & 1u);
  return (unsigned short)(u >> 16);
}

// counted-vmcnt barrier: loads stay in flight across the barrier (T4).
// sched_barrier(0) fences per rule #18 (compiler may hoist past asm waitcnt).
__device__ __forceinline__ void waitbar6() {
  __builtin_amdgcn_sched_barrier(0);
  asm volatile("s_waitcnt vmcnt(6) lgkmcnt(0)" ::: "memory");
  __builtin_amdgcn_s_barrier();
  __builtin_amdgcn_sched_barrier(0);
}
__device__ __forceinline__ void waitbar3() {
  __builtin_amdgcn_sched_barrier(0);
  asm volatile("s_waitcnt vmcnt(3) lgkmcnt(0)" ::: "memory");
  __builtin_amdgcn_s_barrier();
  __builtin_amdgcn_sched_barrier(0);
}
__device__ __forceinline__ void waitbar0() {
  __builtin_amdgcn_sched_barrier(0);
  asm volatile("s_waitcnt vmcnt(0) lgkmcnt(0)" ::: "memory");
  __builtin_amdgcn_s_barrier();
  __builtin_amdgcn_sched_barrier(0);
}

// ---------------- kernel: fused prep (xcvt + weight transpose + labels) ----------------
// blocks [0,4096): x f32 -> bf16
// blocks [4096,4896): W_lvl2 [25][2048][41] -> wlt bf16 [25][64][2048] rows 41..47=0, 48..63 untouched
// blocks [4896,4928): W_root [2048][26] -> wrt bf16 [32][2048] rows 26..31=0
// block 4928: labels normalize + pengl=0
__global__ __launch_bounds__(TB) void k_prep(const float* __restrict__ x,
                                             const float* __restrict__ wl,
                                             const float* __restrict__ wr,
                                             const int* __restrict__ labraw,
                                             unsigned short* __restrict__ xbf,
                                             unsigned short* __restrict__ wlt,
                                             unsigned short* __restrict__ wrt,
                                             int* __restrict__ lab32,
                                             float* __restrict__ pengl) {
  int bid = blockIdx.x, t = threadIdx.x;
  if (bid < 4096) {
    int idx = bid * TB + t;
    const float4* xin = reinterpret_cast<const float4*>(x);
    float4 a = xin[idx * 2], b = xin[idx * 2 + 1];
    uint32_t p0 = f2bf(a.x) | ((uint32_t)f2bf(a.y) << 16);
    uint32_t p1 = f2bf(a.z) | ((uint32_t)f2bf(a.w) << 16);
    uint32_t p2 = f2bf(b.x) | ((uint32_t)f2bf(b.y) << 16);
    uint32_t p3 = f2bf(b.z) | ((uint32_t)f2bf(b.w) << 16);
    reinterpret_cast<uint4*>(xbf)[idx] = make_uint4(p0, p1, p2, p3);
  } else if (bid < 4928) {
    __shared__ float ld_f[2624];
    int b2 = bid - 4096;
    if (b2 < 800) {
      int n = b2 / 32, dt = b2 % 32, d0 = dt * 64;
      const float* src = wl + ((size_t)n * 2048 + d0) * 41;
      for (int i = 0; i < 11; i++) { int lin = t + TB * i; if (lin < 2624) ld_f[lin] = src[lin]; }
      __syncthreads();
      unsigned short* dst = wlt + (size_t)n * 64 * 2048 + d0;
      for (int i = 0; i < 12; i++) {
        int lin = t + TB * i;  // 3072 = 48*64
        int wc = lin >> 6, d = lin & 63;
        float v = (wc < 41) ? ld_f[d * 41 + wc] : 0.f;
        dst[(size_t)wc * 2048 + d] = f2bf(v);
      }
    } else {
      int dt = b2 - 800, d0 = dt * 64;
      const float* src = wr + (size_t)d0 * 26;
      for (int i = 0; i < 7; i++) { int lin = t + TB * i; if (lin < 1664) ld_f[lin] = src[lin]; }
      __syncthreads();
      unsigned short* dst = wrt + d0;
      for (int i = 0; i < 8; i++) {
        int lin = t + TB * i;  // 2048 = 32*64
        int wc = lin >> 6, d = lin & 63;
        float v = (wc < 26) ? ld_f[d * 26 + wc] : 0.f;
        dst[(size_t)wc * 2048 + d] = f2bf(v);
      }
    }
  } else {
    __shared__ int orred;
    if (t == 0) { orred = 0; pengl[0] = 0.f; }
    __syncthreads();
    int acc = 0;
    for (int i = t; i < 2048; i += TB) acc |= labraw[2 * i + 1];
    atomicOr(&orred, acc);
    __syncthreads();
    bool i64 = (orred == 0);
    for (int i = t; i < 4096; i += TB) lab32[i] = i64 ? labraw[2 * i] : labraw[i];
  }
}

// ---------------- kernel: fused root GEMM + softmax + ce_root (no atomics on logits) ----
// 64 blocks x 64 rows; full K=2048 per block; ring-3 depth-2 pipeline (3 loads/thread/stage)
__global__ __launch_bounds__(TB) void k_root(const unsigned short* __restrict__ xbf,
                                             const unsigned short* __restrict__ wrt,
                                             const float* __restrict__ br,
                                             const int* __restrict__ labels,
                                             float* __restrict__ rootp,
                                             float* __restrict__ pengl) {
  __shared__ __align__(16) unsigned char lds3[3][12288];  // 8K x (64 rows) + 4K w (32 rows)
  int r0 = blockIdx.x * 64;
  int tid = threadIdx.x, lane = tid & 63, wave = tid >> 6;
  int wavebase = wave * 64;
  int lq = lane >> 4, lr = lane & 15;
  const unsigned short* xg = xbf + (size_t)r0 * 2048;
  f32x4 acc[2] = {};

#define STAGE_RT(lb, kk)                                                              \
  do {                                                                                \
    _Pragma("unroll")                                                                 \
    for (int i = 0; i < 2; i++) {                                                     \
      int c = i * 256 + tid;                                                          \
      int row = c >> 3, s = c & 7;                                                    \
      const unsigned short* gp = xg + (size_t)row * 2048 + (kk) + ((s ^ (row & 7)) << 3); \
      GLOAD16(gp, (lb) + (size_t)(i * 256 + wavebase) * 16);                          \
    }                                                                                 \
    {                                                                                 \
      int wc = tid >> 3, s = tid & 7;                                                 \
      const unsigned short* gp = wrt + (size_t)wc * 2048 + (kk) + ((s ^ (wc & 7)) << 3); \
      GLOAD16(gp, (lb) + 8192 + (size_t)wavebase * 16);                               \
    }                                                                                 \
  } while (0)

#define COMPUTE_RT(base)                                                              \
  do {                                                                                \
    _Pragma("unroll")                                                                 \
    for (int ks = 0; ks < 2; ks++) {                                                  \
      bf16x8 af[2], bx;                                                               \
      _Pragma("unroll")                                                               \
      for (int mt = 0; mt < 2; mt++) {                                                \
        int wc = mt * 16 + lr;                                                        \
        af[mt] = *reinterpret_cast<const bf16x8*>((base) + 8192 + wc * 128 + ((((ks << 2) | lq) ^ (wc & 7)) << 4)); \
      }                                                                               \
      {                                                                               \
        int row = wavebase / 4 + lr; /* wave*16 + lr */                               \
        bx = *reinterpret_cast<const bf16x8*>((base) + row * 128 + ((((ks << 2) | lq) ^ (row & 7)) << 4)); \
      }                                                                               \
      _Pragma("unroll")                                                               \
      for (int mt = 0; mt < 2; mt++)                                                  \
        acc[mt] = __builtin_amdgcn_mfma_f32_16x16x32_bf16(af[mt], bx, acc[mt], 0, 0, 0); \
    }                                                                                 \
  } while (0)

  STAGE_RT(&lds3[0][0], 0);
  STAGE_RT(&lds3[1][0], 64);
  waitbar3();
  int cur = 0;
#pragma unroll 3
  for (int t = 0; t < 30; ++t) {
    int nx = cur + 2; if (nx >= 3) nx -= 3;
    STAGE_RT(&lds3[nx][0], (t + 2) * 64);
    COMPUTE_RT(&lds3[cur][0]);
    waitbar3();
    ++cur; if (cur == 3) cur = 0;
  }
  COMPUTE_RT(&lds3[cur][0]);  // t=30
  waitbar0();
  ++cur; if (cur == 3) cur = 0;
  COMPUTE_RT(&lds3[cur][0]);  // t=31

  // epilogue: bias(mask), softmax over 26 cols (row in 4 lanes), rootp + ce_root
  float bb[2][4];
#pragma unroll
  for (int mt = 0; mt < 2; mt++)
#pragma unroll
    for (int r = 0; r < 4; r++) {
      int wc = mt * 16 + lq * 4 + r;
      bb[mt][r] = (wc < 26) ? br[wc] : -1e30f;
    }
  int b = r0 + wave * 16 + lr;
  float lg[2][4];
  float m = -1e30f;
#pragma unroll
  for (int mt = 0; mt < 2; mt++)
#pragma unroll
    for (int r = 0; r < 4; r++) {
      float v = acc[mt][r] + bb[mt][r];
      lg[mt][r] = v;
      m = fmaxf(m, v);
    }
  m = fmaxf(m, __shfl_xor(m, 16));
  m = fmaxf(m, __shfl_xor(m, 32));
  float s = 0.f;
#pragma unroll
  for (int mt = 0; mt < 2; mt++)
#pragma unroll
    for (int r = 0; r < 4; r++) s += expf(lg[mt][r] - m);
  s += __shfl_xor(s, 16);
  s += __shfl_xor(s, 32);
  float ls = logf(s);
  int lab = labels[b];
  int j = lab / 40;
  float pen = 0.f;
#pragma unroll
  for (int mt = 0; mt < 2; mt++)
#pragma unroll
    for (int r = 0; r < 4; r++) {
      int wc = mt * 16 + lq * 4 + r;
      float lp = lg[mt][r] - m - ls;
      if (wc < 26) rootp[(size_t)b * 32 + wc] = expf(lp);
      if (wc == j + 1) pen -= lp;
    }
  for (int off = 32; off; off >>= 1) pen += __shfl_down(pen, off);
  float* red = (float*)&lds3[0][0];  // buf0 idle: t=31 computed buf1
  if (lane == 0) red[wave] = pen;
  __syncthreads();
  if (tid == 0) atomicAdd(pengl, (red[0] + red[1] + red[2] + red[3]) * (1.f / 4096.f));
}

// ---------------- kernel: lvl2 grouped GEMM, ring-3 depth-2 counted-vmcnt ----------------
__global__ __launch_bounds__(TB) void k_lvl2(const unsigned short* __restrict__ xbf,
                                             const unsigned short* __restrict__ wlt,
                                             const float* __restrict__ bl,
                                             const int* __restrict__ labels,
                                             const float* __restrict__ rootp,
                                             float* __restrict__ out,
                                             float* __restrict__ pengl) {
  __shared__ __align__(16) unsigned char lds3[3][24576];  // 16K x (128 rows) + 8K w (64 rows)
  int bid = blockIdx.x;                       // 800 = 32 row-tiles * 25 groups
  int swz = (bid & 7) * 100 + (bid >> 3);     // XCD-chunked, bijective (800 = 8*100)
  int rt = swz / 25, n = swz % 25;
  int r0 = rt * 128;
  int tid = threadIdx.x, lane = tid & 63, wave = tid >> 6;
  int wavebase = wave * 64;
  int lq = lane >> 4, lr = lane & 15;
  f32x4 acc[3][2] = {};
  const unsigned short* xg = xbf + (size_t)r0 * 2048;
  const unsigned short* wg = wlt + (size_t)n * 64 * 2048;

  // 6 gload_lds per thread per stage, uniform across waves (vmcnt counting needs this)
#define STAGE_L2(lb, kk)                                                              \
  do {                                                                                \
    _Pragma("unroll")                                                                 \
    for (int i = 0; i < 4; i++) {                                                     \
      int c = i * 256 + tid;                                                          \
      int row = c >> 3, s = c & 7;                                                    \
      const unsigned short* gp = xg + (size_t)row * 2048 + (kk) + ((s ^ (row & 7)) << 3); \
      GLOAD16(gp, (lb) + (size_t)(i * 256 + wavebase) * 16);                          \
    }                                                                                 \
    _Pragma("unroll")                                                                 \
    for (int i = 0; i < 2; i++) {                                                     \
      int c = i * 256 + tid;                                                          \
      int wc = c >> 3, s = c & 7;                                                     \
      const unsigned short* gp = wg + (size_t)wc * 2048 + (kk) + ((s ^ (wc & 7)) << 3); \
      GLOAD16(gp, (lb) + 16384 + (size_t)(i * 256 + wavebase) * 16);                  \
    }                                                                                 \
  } while (0)

#define COMPUTE_L2(base)                                                              \
  do {                                                                                \
    _Pragma("unroll")                                                                 \
    for (int ks = 0; ks < 2; ks++) {                                                  \
      bf16x8 af[3], bx[2];                                                            \
      _Pragma("unroll")                                                               \
      for (int mt = 0; mt < 3; mt++) {                                                \
        int wc = mt * 16 + lr;                                                        \
        af[mt] = *reinterpret_cast<const bf16x8*>((base) + 16384 + wc * 128 + ((((ks << 2) | lq) ^ (wc & 7)) << 4)); \
      }                                                                               \
      _Pragma("unroll")                                                               \
      for (int nt = 0; nt < 2; nt++) {                                                \
        int row = wave * 32 + nt * 16 + lr;                                           \
        bx[nt] = *reinterpret_cast<const bf16x8*>((base) + row * 128 + ((((ks << 2) | lq) ^ (row & 7)) << 4)); \
      }                                                                               \
      _Pragma("unroll")                                                               \
      for (int mt = 0; mt < 3; mt++)                                                  \
        _Pragma("unroll")                                                             \
        for (int nt = 0; nt < 2; nt++)                                                \
          acc[mt][nt] = __builtin_amdgcn_mfma_f32_16x16x32_bf16(af[mt], bx[nt], acc[mt][nt], 0, 0, 0); \
    }                                                                                 \
  } while (0)

  STAGE_L2(&lds3[0][0], 0);
  STAGE_L2(&lds3[1][0], 64);
  waitbar6();
  int cur = 0;
#pragma unroll 3
  for (int t = 0; t < 30; ++t) {
    int nx = cur + 2; if (nx >= 3) nx -= 3;
    STAGE_L2(&lds3[nx][0], (t + 2) * 64);
    COMPUTE_L2(&lds3[cur][0]);
    waitbar6();
    ++cur; if (cur == 3) cur = 0;
  }
  COMPUTE_L2(&lds3[cur][0]);  // t=30
  waitbar0();
  ++cur; if (cur == 3) cur = 0;
  COMPUTE_L2(&lds3[cur][0]);  // t=31

  // epilogue: bias, row softmax (row lives in 4 lanes: q groups), out, penalty
  float bb[3][4];
#pragma unroll
  for (int mt = 0; mt < 3; mt++)
#pragma unroll
    for (int r = 0; r < 4; r++) {
      int wc = mt * 16 + lq * 4 + r;
      bb[mt][r] = (wc < 41) ? bl[n * 41 + wc] : -1e30f;
    }
  float pen = 0.f;
#pragma unroll
  for (int nt = 0; nt < 2; nt++) {
    int b = r0 + wave * 32 + nt * 16 + lr;
    float lg[3][4];
    float m = -1e30f;
#pragma unroll
    for (int mt = 0; mt < 3; mt++)
#pragma unroll
      for (int r = 0; r < 4; r++) {
        float v = acc[mt][nt][r] + bb[mt][r];
        lg[mt][r] = v;
        m = fmaxf(m, v);
      }
    m = fmaxf(m, __shfl_xor(m, 16));
    m = fmaxf(m, __shfl_xor(m, 32));
    float s = 0.f;
#pragma unroll
    for (int mt = 0; mt < 3; mt++)
#pragma unroll
      for (int r = 0; r < 4; r++) s += expf(lg[mt][r] - m);
    s += __shfl_xor(s, 16);
    s += __shfl_xor(s, 32);
    float ls = logf(s);
    float rp = rootp[(size_t)b * 32 + (n + 1)];
    int lab = labels[b];
    int j = lab / 40;
    int sub = (j == n) ? (lab - j * 40 + 1) : 0;
#pragma unroll
    for (int mt = 0; mt < 3; mt++)
#pragma unroll
      for (int r = 0; r < 4; r++) {
        int wc = mt * 16 + lq * 4 + r;
        float lp = lg[mt][r] - m - ls;
        if (wc >= 1 && wc < 41) out[(size_t)b * 1000 + n * 40 + wc - 1] = expf(lp) * rp;
        if (wc == sub) pen -= lp;
      }
  }
  for (int off = 32; off; off >>= 1) pen += __shfl_down(pen, off);
  float* red = (float*)&lds3[0][0];  // buf0 idle: t=31 computed buf1
  if (lane == 0) red[wave] = pen;
  __syncthreads();
  if (tid == 0) atomicAdd(pengl, (red[0] + red[1] + red[2] + red[3]) * (1.f / 8192.f));
}

extern "C" void kernel_launch(void* const* d_in, const int* in_sizes, int n_in,
                              void* d_out, int out_size, void* d_ws, size_t ws_size,
                              hipStream_t stream) {
  const float* x = (const float*)d_in[0];
  const int* labels_raw = (const int*)d_in[1];
  const float* wroot = (const float*)d_in[2];
  const float* broot = (const float*)d_in[3];
  const float* wlvl2 = (const float*)d_in[4];
  const float* blvl2 = (const float*)d_in[5];
  float* out = (float*)d_out;
  float* pengl = out + 4096000;

  char* ws = (char*)d_ws;
  unsigned short* xbf = (unsigned short*)ws;                               // 16,777,216 B
  unsigned short* wlt = (unsigned short*)(ws + 16777216);                  //  6,553,600 B (25x64x2048)
  unsigned short* wrt = (unsigned short*)(ws + 16777216 + 6553600);        //    131,072 B
  float* rootp = (float*)(ws + 16777216 + 6553600 + 131072);               //    524,288 B
  int* lab32 = (int*)(ws + 16777216 + 6553600 + 131072 + 524288);          //     16,384 B

  k_prep<<<4929, TB, 0, stream>>>(x, wlvl2, wroot, labels_raw, xbf, wlt, wrt, lab32, pengl);
  k_root<<<64, TB, 0, stream>>>(xbf, wrt, broot, lab32, rootp, pengl);
  k_lvl2<<<800, TB, 0, stream>>>(xbf, wlt, blvl2, lab32, rootp, out, pengl);
}

// Round 6
// 147.283 us; speedup vs baseline: 1.2524x; 1.0372x over previous
//
#include <hip/hip_runtime.h>
#include <stdint.h>

#define TB 256

typedef __bf16 bf16x8 __attribute__((ext_vector_type(8)));
typedef float f32x4 __attribute__((ext_vector_type(4)));

#define AS1 __attribute__((address_space(1)))
#define AS3 __attribute__((address_space(3)))
// direct global->LDS, 16B per lane; LDS dest = wave-uniform base + lane*16
#define GLOAD16(gp, lp) __builtin_amdgcn_global_load_lds( \
    (const AS1 unsigned int*)(gp), (AS3 unsigned int*)(lp), 16, 0, 0)

__device__ __forceinline__ unsigned short f2bf(float f) {
  uint32_t u = __builtin_bit_cast(uint32_t, f);
  u += 0x7fffu + ((u >> 16) & 1u);
  return (unsigned short)(u >> 16);
}

// counted-vmcnt barriers (T4); sched_barrier(0) fences per rule #18
__device__ __forceinline__ void waitbar3() {
  __builtin_amdgcn_sched_barrier(0);
  asm volatile("s_waitcnt vmcnt(3) lgkmcnt(0)" ::: "memory");
  __builtin_amdgcn_s_barrier();
  __builtin_amdgcn_sched_barrier(0);
}
__device__ __forceinline__ void waitbar0() {
  __builtin_amdgcn_sched_barrier(0);
  asm volatile("s_waitcnt vmcnt(0) lgkmcnt(0)" ::: "memory");
  __builtin_amdgcn_s_barrier();
  __builtin_amdgcn_sched_barrier(0);
}

// ---------------- kernel: fused prep ----------------
// [0,4096): x f32 -> bf16
// [4096,4896): W_lvl2 [25][2048][41] -> wlt bf16 [26][48][2048] (cols 41..47 = 0)
// [4896,4928): W_root [2048][26] -> wrt bf16 [32][2048] (rows 26..31 = 0)
// 4928: labels normalize + pengl=0 ; 4929: zero wlt group 25
__global__ __launch_bounds__(TB) void k_prep(const float* __restrict__ x,
                                             const float* __restrict__ wl,
                                             const float* __restrict__ wr,
                                             const int* __restrict__ labraw,
                                             unsigned short* __restrict__ xbf,
                                             unsigned short* __restrict__ wlt,
                                             unsigned short* __restrict__ wrt,
                                             int* __restrict__ lab32,
                                             float* __restrict__ pengl) {
  int bid = blockIdx.x, t = threadIdx.x;
  if (bid < 4096) {
    int idx = bid * TB + t;
    const float4* xin = reinterpret_cast<const float4*>(x);
    float4 a = xin[idx * 2], b = xin[idx * 2 + 1];
    uint32_t p0 = f2bf(a.x) | ((uint32_t)f2bf(a.y) << 16);
    uint32_t p1 = f2bf(a.z) | ((uint32_t)f2bf(a.w) << 16);
    uint32_t p2 = f2bf(b.x) | ((uint32_t)f2bf(b.y) << 16);
    uint32_t p3 = f2bf(b.z) | ((uint32_t)f2bf(b.w) << 16);
    reinterpret_cast<uint4*>(xbf)[idx] = make_uint4(p0, p1, p2, p3);
  } else if (bid < 4928) {
    __shared__ float ld_f[2624];
    int b2 = bid - 4096;
    if (b2 < 800) {
      int n = b2 / 32, dt = b2 % 32, d0 = dt * 64;
      const float* src = wl + ((size_t)n * 2048 + d0) * 41;
      for (int i = 0; i < 11; i++) { int lin = t + TB * i; if (lin < 2624) ld_f[lin] = src[lin]; }
      __syncthreads();
      unsigned short* dst = wlt + (size_t)n * 48 * 2048 + d0;
      for (int i = 0; i < 12; i++) {
        int lin = t + TB * i;  // 3072 = 48*64
        int wc = lin >> 6, d = lin & 63;
        float v = (wc < 41) ? ld_f[d * 41 + wc] : 0.f;
        dst[(size_t)wc * 2048 + d] = f2bf(v);
      }
    } else {
      int dt = b2 - 800, d0 = dt * 64;
      const float* src = wr + (size_t)d0 * 26;
      for (int i = 0; i < 7; i++) { int lin = t + TB * i; if (lin < 1664) ld_f[lin] = src[lin]; }
      __syncthreads();
      unsigned short* dst = wrt + d0;
      for (int i = 0; i < 8; i++) {
        int lin = t + TB * i;  // 2048 = 32*64
        int wc = lin >> 6, d = lin & 63;
        float v = (wc < 26) ? ld_f[d * 26 + wc] : 0.f;
        dst[(size_t)wc * 2048 + d] = f2bf(v);
      }
    }
  } else if (bid == 4928) {
    __shared__ int orred;
    if (t == 0) { orred = 0; pengl[0] = 0.f; }
    __syncthreads();
    int acc = 0;
    for (int i = t; i < 2048; i += TB) acc |= labraw[2 * i + 1];
    atomicOr(&orred, acc);
    __syncthreads();
    bool i64 = (orred == 0);
    for (int i = t; i < 4096; i += TB) lab32[i] = i64 ? labraw[2 * i] : labraw[i];
  } else {
    uint4* p = reinterpret_cast<uint4*>(wlt + (size_t)25 * 48 * 2048);
    uint4 z = make_uint4(0, 0, 0, 0);
    for (int i = t; i < 12288; i += TB) p[i] = z;
  }
}

// ---------------- kernel: root GEMM + softmax + ce_root ----------------
// 256 blocks x 512 threads; 16 rows/block; 8 waves split K 8-way per K-step(256)
__global__ __launch_bounds__(512) void k_root(const unsigned short* __restrict__ xbf,
                                              const unsigned short* __restrict__ wrt,
                                              const float* __restrict__ br,
                                              const int* __restrict__ labels,
                                              float* __restrict__ rootp,
                                              float* __restrict__ pengl) {
  __shared__ __align__(16) unsigned char lds3[3][24576];  // x 8K @0, w 16K @8192
  int r0 = blockIdx.x * 16;
  int tid = threadIdx.x, lane = tid & 63, wave = tid >> 6;  // wave in [0,8)
  int lq = lane >> 4, lr = lane & 15;
  const unsigned short* xg = xbf + (size_t)r0 * 2048;
  f32x4 acc[2] = {};

#define STAGE_RT(lb, kk)                                                              \
  do {                                                                                \
    { /* x: 512 chunks, 1/thread */                                                   \
      int row = tid >> 5, s = tid & 31;                                               \
      const unsigned short* gp = xg + (size_t)row * 2048 + (kk) + ((s ^ row) << 3);   \
      GLOAD16(gp, (lb) + (size_t)tid * 16);                                           \
    }                                                                                 \
    _Pragma("unroll")                                                                 \
    for (int i = 0; i < 2; i++) { /* w: 1024 chunks, 2/thread */                      \
      int idx = i * 512 + tid;                                                        \
      int wc = idx >> 5, s = idx & 31;                                                \
      const unsigned short* gp = wrt + (size_t)wc * 2048 + (kk) + ((s ^ (wc & 31)) << 3); \
      GLOAD16(gp, (lb) + 8192 + (size_t)idx * 16);                                    \
    }                                                                                 \
  } while (0)

#define COMPUTE_RT(base)                                                              \
  do {                                                                                \
    int g = (wave << 2) | lq; /* this wave's k-chunk in [0,32) */                     \
    bf16x8 af[2], bx;                                                                 \
    _Pragma("unroll")                                                                 \
    for (int mt = 0; mt < 2; mt++) {                                                  \
      int c = mt * 16 + lr;                                                           \
      af[mt] = *reinterpret_cast<const bf16x8*>((base) + 8192 + c * 512 + ((g ^ (c & 31)) << 4)); \
    }                                                                                 \
    bx = *reinterpret_cast<const bf16x8*>((base) + lr * 512 + ((g ^ lr) << 4));       \
    _Pragma("unroll")                                                                 \
    for (int mt = 0; mt < 2; mt++)                                                    \
      acc[mt] = __builtin_amdgcn_mfma_f32_16x16x32_bf16(af[mt], bx, acc[mt], 0, 0, 0); \
  } while (0)

  STAGE_RT(&lds3[0][0], 0);
  STAGE_RT(&lds3[1][0], 256);
  waitbar3();
  int cur = 0;
#pragma unroll 3
  for (int t = 0; t < 6; ++t) {
    int nx = cur + 2; if (nx >= 3) nx -= 3;
    STAGE_RT(&lds3[nx][0], (t + 2) * 256);
    COMPUTE_RT(&lds3[cur][0]);
    waitbar3();
    ++cur; if (cur == 3) cur = 0;
  }
  COMPUTE_RT(&lds3[cur][0]);  // t=6
  waitbar0();
  ++cur; if (cur == 3) cur = 0;
  COMPUTE_RT(&lds3[cur][0]);  // t=7
  __syncthreads();

  // cross-wave reduction of the 8 K-slices
  float* red = (float*)&lds3[0][0];  // 16 KB
  int li = (wave * 64 + lane) * 8;
#pragma unroll
  for (int mt = 0; mt < 2; mt++)
#pragma unroll
    for (int r = 0; r < 4; r++) red[li + mt * 4 + r] = acc[mt][r];
  __syncthreads();
  if (wave == 0) {
    float lg[2][4];
    float m = -1e30f;
#pragma unroll
    for (int mt = 0; mt < 2; mt++)
#pragma unroll
      for (int r = 0; r < 4; r++) {
        float v = 0.f;
#pragma unroll
        for (int w = 0; w < 8; w++) v += red[(w * 64 + lane) * 8 + mt * 4 + r];
        int wc = mt * 16 + lq * 4 + r;
        v += (wc < 26) ? br[wc] : -1e30f;
        lg[mt][r] = v;
        m = fmaxf(m, v);
      }
    m = fmaxf(m, __shfl_xor(m, 16));
    m = fmaxf(m, __shfl_xor(m, 32));
    float s = 0.f;
#pragma unroll
    for (int mt = 0; mt < 2; mt++)
#pragma unroll
      for (int r = 0; r < 4; r++) s += expf(lg[mt][r] - m);
    s += __shfl_xor(s, 16);
    s += __shfl_xor(s, 32);
    float ls = logf(s);
    int b = r0 + lr;
    int lab = labels[b];
    int j = lab / 40;
    float pen = 0.f;
#pragma unroll
    for (int mt = 0; mt < 2; mt++)
#pragma unroll
      for (int r = 0; r < 4; r++) {
        int wc = mt * 16 + lq * 4 + r;
        float lp = lg[mt][r] - m - ls;
        if (wc < 26) rootp[(size_t)b * 32 + wc] = expf(lp);
        if (wc == j + 1) pen -= lp;
      }
    for (int off = 32; off; off >>= 1) pen += __shfl_down(pen, off);
    if (lane == 0) atomicAdd(pengl, pen * (1.f / 4096.f));
  }
}

// ---------------- kernel: lvl2 grouped GEMM, M=128 x N=96 (2 groups), 2x2 waves ----
__global__ __launch_bounds__(TB) void k_lvl2(const unsigned short* __restrict__ xbf,
                                             const unsigned short* __restrict__ wlt,
                                             const float* __restrict__ bl,
                                             const int* __restrict__ labels,
                                             const float* __restrict__ rootp,
                                             float* __restrict__ out,
                                             float* __restrict__ pengl) {
  __shared__ __align__(16) unsigned char ldsb[2][28672];  // x 16K @0, w 12K @16384
  int bid = blockIdx.x;                      // 416 = 32 row-tiles * 13 group-pairs
  int swz = (bid & 7) * 52 + (bid >> 3);     // XCD-chunked, bijective (416 = 8*52)
  int rt = swz / 13, gp = swz % 13;
  int r0 = rt * 128, n0 = gp * 2;
  int tid = threadIdx.x, lane = tid & 63, wave = tid >> 6;
  int wr = wave >> 1, wcq = wave & 1;        // 2x2 wave grid: rows wr*64, cols wcq*48
  int lq = lane >> 4, lr = lane & 15;
  f32x4 acc[3][4] = {};
  const unsigned short* xg = xbf + (size_t)r0 * 2048;
  const unsigned short* wg = wlt + (size_t)n0 * 48 * 2048;  // 96 contiguous rows

  // 7 gload_lds per thread per stage, uniform across waves
#define STAGE_L2(lb, kk)                                                              \
  do {                                                                                \
    _Pragma("unroll")                                                                 \
    for (int i = 0; i < 4; i++) { /* x: 1024 chunks */                                \
      int idx = i * 256 + tid;                                                        \
      int row = idx >> 3, s = idx & 7;                                                \
      const unsigned short* gp = xg + (size_t)row * 2048 + (kk) + ((s ^ (row & 7)) << 3); \
      GLOAD16(gp, (lb) + (size_t)idx * 16);                                           \
    }                                                                                 \
    _Pragma("unroll")                                                                 \
    for (int i = 0; i < 3; i++) { /* w: 768 chunks (96 rows) */                       \
      int idx = i * 256 + tid;                                                        \
      int wc = idx >> 3, s = idx & 7;                                                 \
      const unsigned short* gp = wg + (size_t)wc * 2048 + (kk) + ((s ^ (wc & 7)) << 3); \
      GLOAD16(gp, (lb) + 16384 + (size_t)idx * 16);                                   \
    }                                                                                 \
  } while (0)

#define COMPUTE_L2(base)                                                              \
  do {                                                                                \
    _Pragma("unroll")                                                                 \
    for (int ks = 0; ks < 2; ks++) {                                                  \
      int g = (ks << 2) | lq;                                                         \
      bf16x8 af[3], bx[4];                                                            \
      _Pragma("unroll")                                                               \
      for (int mt = 0; mt < 3; mt++) {                                                \
        int c = wcq * 48 + mt * 16 + lr;                                              \
        af[mt] = *reinterpret_cast<const bf16x8*>((base) + 16384 + c * 128 + ((g ^ (c & 7)) << 4)); \
      }                                                                               \
      _Pragma("unroll")                                                               \
      for (int nt = 0; nt < 4; nt++) {                                                \
        int row = wr * 64 + nt * 16 + lr;                                             \
        bx[nt] = *reinterpret_cast<const bf16x8*>((base) + row * 128 + ((g ^ (row & 7)) << 4)); \
      }                                                                               \
      _Pragma("unroll")                                                               \
      for (int mt = 0; mt < 3; mt++)                                                  \
        _Pragma("unroll")                                                             \
        for (int nt = 0; nt < 4; nt++)                                                \
          acc[mt][nt] = __builtin_amdgcn_mfma_f32_16x16x32_bf16(af[mt], bx[nt], acc[mt][nt], 0, 0, 0); \
    }                                                                                 \
  } while (0)

  STAGE_L2(&ldsb[0][0], 0);
  waitbar0();
#pragma unroll 2
  for (int t = 0; t < 32; ++t) {
    if (t < 31) STAGE_L2(&ldsb[(t + 1) & 1][0], (t + 1) * 64);
    COMPUTE_L2(&ldsb[t & 1][0]);
    waitbar0();
  }

  // epilogue: per-wave group n = n0 + wcq; softmax per row within the wave
  int n = n0 + wcq;
  bool valid = (n < 25);
  float bb[3][4];
#pragma unroll
  for (int mt = 0; mt < 3; mt++)
#pragma unroll
    for (int r = 0; r < 4; r++) {
      int wcg = mt * 16 + lq * 4 + r;
      bb[mt][r] = (valid && wcg < 41) ? bl[n * 41 + wcg] : -1e30f;
    }
  float pen = 0.f;
#pragma unroll
  for (int nt = 0; nt < 4; nt++) {
    int b = r0 + wr * 64 + nt * 16 + lr;
    float lg[3][4];
    float m = -1e30f;
#pragma unroll
    for (int mt = 0; mt < 3; mt++)
#pragma unroll
      for (int r = 0; r < 4; r++) {
        float v = acc[mt][nt][r] + bb[mt][r];
        lg[mt][r] = v;
        m = fmaxf(m, v);
      }
    m = fmaxf(m, __shfl_xor(m, 16));
    m = fmaxf(m, __shfl_xor(m, 32));
    float s = 0.f;
#pragma unroll
    for (int mt = 0; mt < 3; mt++)
#pragma unroll
      for (int r = 0; r < 4; r++) s += expf(lg[mt][r] - m);
    s += __shfl_xor(s, 16);
    s += __shfl_xor(s, 32);
    float ls = logf(s);
    float rp = valid ? rootp[(size_t)b * 32 + (n + 1)] : 0.f;
    int lab = labels[b];
    int j = lab / 40;
    int sub = (j == n) ? (lab - j * 40 + 1) : 0;
#pragma unroll
    for (int mt = 0; mt < 3; mt++)
#pragma unroll
      for (int r = 0; r < 4; r++) {
        int wcg = mt * 16 + lq * 4 + r;
        float lp = lg[mt][r] - m - ls;
        if (valid && wcg >= 1 && wcg < 41) out[(size_t)b * 1000 + n * 40 + wcg - 1] = expf(lp) * rp;
        if (valid && wcg == sub) pen -= lp;
      }
  }
  for (int off = 32; off; off >>= 1) pen += __shfl_down(pen, off);
  float* red = (float*)&ldsb[0][0];  // safe: last waitbar0 drained all LDS reads
  if (lane == 0) red[wave] = pen;
  __syncthreads();
  if (tid == 0) atomicAdd(pengl, (red[0] + red[1] + red[2] + red[3]) * (1.f / 8192.f));
}

extern "C" void kernel_launch(void* const* d_in, const int* in_sizes, int n_in,
                              void* d_out, int out_size, void* d_ws, size_t ws_size,
                              hipStream_t stream) {
  const float* x = (const float*)d_in[0];
  const int* labels_raw = (const int*)d_in[1];
  const float* wroot = (const float*)d_in[2];
  const float* broot = (const float*)d_in[3];
  const float* wlvl2 = (const float*)d_in[4];
  const float* blvl2 = (const float*)d_in[5];
  float* out = (float*)d_out;
  float* pengl = out + 4096000;

  char* ws = (char*)d_ws;
  unsigned short* xbf = (unsigned short*)ws;                    // 16,777,216 B
  unsigned short* wlt = (unsigned short*)(ws + 16777216);       //  5,111,808 B (26x48x2048)
  unsigned short* wrt = (unsigned short*)(ws + 21889024);       //    131,072 B (32x2048)
  float* rootp = (float*)(ws + 22020096);                       //    524,288 B
  int* lab32 = (int*)(ws + 22544384);                           //     16,384 B

  k_prep<<<4930, TB, 0, stream>>>(x, wlvl2, wroot, labels_raw, xbf, wlt, wrt, lab32, pengl);
  k_root<<<256, 512, 0, stream>>>(xbf, wrt, broot, lab32, rootp, pengl);
  k_lvl2<<<416, TB, 0, stream>>>(xbf, wlt, blvl2, lab32, rootp, out, pengl);
}